// Round 12
// baseline (46.442 us; speedup 1.0000x reference)
//
#include <hip/hip_runtime.h>

// ConvDistanceTransform closed form:
//   D = Chebyshev distance transform of seeds (exact, separable)
//   i = (D-1)/3 ; out = 3.5*i - 0.35*log( sum_{q in 7x7, D(q)<=3i} exp(-|p-q|_2/0.35) )
// Distances saturate at 127. d1 stored as u8 (8-col guards of 0). k_fused:
// 32-col x 128-row tiles; s1 (u16, 127-padded 11 top / 12 bottom rows) ->
// column pass as 5-row shared-register-window tasks (prefix k<=8 via
// offset-immediate ds_reads, tail chunks of 4 k's with shared 16-row window)
// -> macro-unrolled u8 SWAR epilogue (4 weight classes, err <= 0.375).

typedef unsigned short u16x4 __attribute__((ext_vector_type(4)));

#define BIGV (1 << 20)
#define ROWB 272  // u8 d1 row: 8 guard + 256 + 8 guard
#define CHB (256 * ROWB)

// ---------- Kernel A: per-row 1-D distance, wave-per-row register scans ----------
__global__ __launch_bounds__(256) void k_rowdist(const float* __restrict__ img,
                                                 unsigned char* __restrict__ d1) {
  const int lane = threadIdx.x & 63;
  const int wv = threadIdx.x >> 6;
  const int row = blockIdx.x * 4 + wv;  // ch*256 + y
  const int x0 = lane * 4;

  const float4 v = *reinterpret_cast<const float4*>(&img[(size_t)row * 256 + x0]);

  int c0 = (v.x != 0.0f) ? -x0 : BIGV;
  int c1 = (v.y != 0.0f) ? -(x0 + 1) : BIGV;
  int c2 = (v.z != 0.0f) ? -(x0 + 2) : BIGV;
  int c3 = (v.w != 0.0f) ? -(x0 + 3) : BIGV;
  const int p0 = c0;
  const int p1 = min(c1, p0);
  const int p2 = min(c2, p1);
  const int p3 = min(c3, p2);
  int incl = p3;
#pragma unroll
  for (int off = 1; off < 64; off <<= 1) {
    int o = __shfl_up(incl, off, 64);
    if (lane >= off) incl = min(incl, o);
  }
  int excl = __shfl_up(incl, 1, 64);
  if (lane == 0) excl = BIGV;
  const int df0 = x0 + min(p0, excl);
  const int df1 = x0 + 1 + min(p1, excl);
  const int df2 = x0 + 2 + min(p2, excl);
  const int df3 = x0 + 3 + min(p3, excl);

  int g0 = (v.x != 0.0f) ? x0 : BIGV;
  int g1 = (v.y != 0.0f) ? (x0 + 1) : BIGV;
  int g2 = (v.z != 0.0f) ? (x0 + 2) : BIGV;
  int g3 = (v.w != 0.0f) ? (x0 + 3) : BIGV;
  const int q3 = g3;
  const int q2 = min(g2, q3);
  const int q1 = min(g1, q2);
  const int q0 = min(g0, q1);
  int incl2 = q0;
#pragma unroll
  for (int off = 1; off < 64; off <<= 1) {
    int o = __shfl_down(incl2, off, 64);
    if (lane < 64 - off) incl2 = min(incl2, o);
  }
  int excl2 = __shfl_down(incl2, 1, 64);
  if (lane == 63) excl2 = BIGV;
  const int db0 = min(q0, excl2) - x0;
  const int db1 = min(q1, excl2) - (x0 + 1);
  const int db2 = min(q2, excl2) - (x0 + 2);
  const int db3 = min(q3, excl2) - (x0 + 3);

  const unsigned int d0 = (unsigned int)min(min(df0, db0), 127);
  const unsigned int d1v = (unsigned int)min(min(df1, db1), 127);
  const unsigned int d2 = (unsigned int)min(min(df2, db2), 127);
  const unsigned int d3 = (unsigned int)min(min(df3, db3), 127);
  const int ch = row >> 8, y = row & 255;
  const size_t base = (size_t)ch * CHB + (size_t)y * ROWB;
  *reinterpret_cast<unsigned int*>(&d1[base + 8 + x0]) =
      d0 | (d1v << 8) | (d2 << 16) | (d3 << 24);
  // guards = 0 (ghost cols handled by direct 127 writes in k_fused)
  if (lane < 2)
    *reinterpret_cast<unsigned int*>(&d1[base + lane * 4]) = 0u;
  else if (lane >= 62)
    *reinterpret_cast<unsigned int*>(&d1[base + 264 + (lane - 62) * 4]) = 0u;
}

// ---- epilogue tap-row macros (unchanged, proven) ----
#define TAPROW(s_, t_, A0, A1, A2, A3, A4, A5, A6)                              \
  do {                                                                          \
    const unsigned int r0_ = R[(s_) + (t_)][0];                                 \
    const unsigned int r1_ = R[(s_) + (t_)][1];                                 \
    const unsigned int r2_ = R[(s_) + (t_)][2];                                 \
    A0 += (((__builtin_amdgcn_alignbyte(r1_, r0_, 1) + Cp) & 0x80808080u) >> 7);\
    A1 += (((__builtin_amdgcn_alignbyte(r1_, r0_, 2) + Cp) & 0x80808080u) >> 7);\
    A2 += (((__builtin_amdgcn_alignbyte(r1_, r0_, 3) + Cp) & 0x80808080u) >> 7);\
    A3 += (((r1_ + Cp) & 0x80808080u) >> 7);                                    \
    A4 += (((__builtin_amdgcn_alignbyte(r2_, r1_, 1) + Cp) & 0x80808080u) >> 7);\
    A5 += (((__builtin_amdgcn_alignbyte(r2_, r1_, 2) + Cp) & 0x80808080u) >> 7);\
    A6 += (((__builtin_amdgcn_alignbyte(r2_, r1_, 3) + Cp) & 0x80808080u) >> 7);\
  } while (0)

#define TAPROWC(s_, t_, A0, A1, A2, A4, A5, A6)                                 \
  do {                                                                          \
    const unsigned int r0_ = R[(s_) + (t_)][0];                                 \
    const unsigned int r1_ = R[(s_) + (t_)][1];                                 \
    const unsigned int r2_ = R[(s_) + (t_)][2];                                 \
    A0 += (((__builtin_amdgcn_alignbyte(r1_, r0_, 1) + Cp) & 0x80808080u) >> 7);\
    A1 += (((__builtin_amdgcn_alignbyte(r1_, r0_, 2) + Cp) & 0x80808080u) >> 7);\
    A2 += (((__builtin_amdgcn_alignbyte(r1_, r0_, 3) + Cp) & 0x80808080u) >> 7);\
    A4 += (((__builtin_amdgcn_alignbyte(r2_, r1_, 1) + Cp) & 0x80808080u) >> 7);\
    A5 += (((__builtin_amdgcn_alignbyte(r2_, r1_, 2) + Cp) & 0x80808080u) >> 7);\
    A6 += (((__builtin_amdgcn_alignbyte(r2_, r1_, 3) + Cp) & 0x80808080u) >> 7);\
  } while (0)

#define EPI(s_)                                                                 \
  do {                                                                          \
    const unsigned int Dc = R[(s_) + 3][1];                                     \
    const int d0_ = (int)(Dc & 255u);                                           \
    const int d1_ = (int)((Dc >> 8) & 255u);                                    \
    const int d2_ = (int)((Dc >> 16) & 255u);                                   \
    const int d3_ = (int)(Dc >> 24);                                            \
    const int i0_ = (max(d0_ - 1, 0) * 86) >> 8;                                \
    const int i1_ = (max(d1_ - 1, 0) * 86) >> 8;                                \
    const int i2_ = (max(d2_ - 1, 0) * 86) >> 8;                                \
    const int i3_ = (max(d3_ - 1, 0) * 86) >> 8;                                \
    const unsigned int Cp = (unsigned int)(127 - 3 * i0_) |                     \
                            ((unsigned int)(127 - 3 * i1_) << 8) |              \
                            ((unsigned int)(127 - 3 * i2_) << 16) |             \
                            ((unsigned int)(127 - 3 * i3_) << 24);              \
    unsigned int aA = 0, aB = 0, aC = 0, aD = 0;                                \
    TAPROW(s_, 0, aD, aD, aC, aC, aC, aD, aD);                                  \
    TAPROW(s_, 1, aD, aC, aB, aB, aB, aC, aD);                                  \
    TAPROW(s_, 2, aC, aB, aA, aA, aA, aB, aC);                                  \
    TAPROWC(s_, 3, aC, aB, aA, aA, aB, aC);                                     \
    TAPROW(s_, 4, aC, aB, aA, aA, aA, aB, aC);                                  \
    TAPROW(s_, 5, aD, aC, aB, aB, aB, aC, aD);                                  \
    TAPROW(s_, 6, aD, aD, aC, aC, aC, aD, aD);                                  \
    const float s0_ = fmaf((float)(aA & 255u), wA,                              \
                     fmaf((float)(aB & 255u), wB,                               \
                     fmaf((float)(aC & 255u), wC, (float)(aD & 255u) * wD)));   \
    const float s1f_ = fmaf((float)((aA >> 8) & 255u), wA,                      \
                      fmaf((float)((aB >> 8) & 255u), wB,                       \
                      fmaf((float)((aC >> 8) & 255u), wC,                       \
                           (float)((aD >> 8) & 255u) * wD)));                   \
    const float s2_ = fmaf((float)((aA >> 16) & 255u), wA,                      \
                     fmaf((float)((aB >> 16) & 255u), wB,                       \
                     fmaf((float)((aC >> 16) & 255u), wC,                       \
                          (float)((aD >> 16) & 255u) * wD)));                   \
    const float s3_ = fmaf((float)(aA >> 24), wA,                               \
                     fmaf((float)(aB >> 24), wB,                                \
                     fmaf((float)(aC >> 24), wC, (float)(aD >> 24) * wD)));     \
    const float cv0_ = W4 - s0_, cv1_ = W4 - s1f_;                              \
    const float cv2_ = W4 - s2_, cv3_ = W4 - s3_;                               \
    const float e0_ = fmaf(3.5f, (float)i0_, -0.35f * __logf(fmaxf(cv0_, 1e-30f))); \
    const float e1_ = fmaf(3.5f, (float)i1_, -0.35f * __logf(fmaxf(cv1_, 1e-30f))); \
    const float e2_ = fmaf(3.5f, (float)i2_, -0.35f * __logf(fmaxf(cv2_, 1e-30f))); \
    const float e3_ = fmaf(3.5f, (float)i3_, -0.35f * __logf(fmaxf(cv3_, 1e-30f))); \
    const float4 o4_ = make_float4(                                             \
        (d0_ > 0 && cv0_ > 1e-6f) ? e0_ : 0.0f,                                 \
        (d1_ > 0 && cv1_ > 1e-6f) ? e1_ : 0.0f,                                 \
        (d2_ > 0 && cv2_ > 1e-6f) ? e2_ : 0.0f,                                 \
        (d3_ > 0 && cv3_ > 1e-6f) ? e3_ : 0.0f);                                \
    *reinterpret_cast<float4*>(&out[obase + (size_t)(s_) * 256]) = o4_;         \
  } while (0)

#define LDQ(off) (*reinterpret_cast<const u16x4*>(&s1[(off)]))
#define EMIN __builtin_elementwise_min
#define EMAX __builtin_elementwise_max

// prefix output: min over dy in [-8,8] of max(|dy|, window row); a8 = center
#define PFX(OUT, a0, a1, a2, a3, a4, a5, a6, a7, a8, a9, a10, a11, a12, a13,    \
            a14, a15, a16)                                                      \
  u16x4 OUT = EMIN(                                                             \
      EMIN(EMIN(EMIN(EMAX(a7, K1), EMAX(a9, K1)),                               \
                EMIN(EMAX(a6, K2), EMAX(a10, K2))),                             \
           EMIN(EMIN(EMAX(a5, K3), EMAX(a11, K3)),                              \
                EMIN(EMAX(a4, K4), EMAX(a12, K4)))),                            \
      EMIN(EMIN(EMIN(EMAX(a3, K5), EMAX(a13, K5)),                              \
                EMIN(EMAX(a2, K6), EMAX(a14, K6))),                             \
           EMIN(EMIN(EMAX(a1, K7), EMAX(a15, K7)),                              \
                EMIN(EMAX(a0, K8), EMAX(a16, K8)))));                           \
  OUT = EMIN(OUT, a8)

// tail chunk combine for one output row
#define TUP(OUT, b3, b2, b1, b0, d0, d1, d2, d3)                                \
  OUT = EMIN(OUT, EMIN(EMIN(EMIN(EMAX(b3, Kc0), EMAX(b2, Kc1)),                 \
                            EMIN(EMAX(b1, Kc2), EMAX(b0, Kc3))),                \
                       EMIN(EMIN(EMAX(d0, Kc0), EMAX(d1, Kc1)),                 \
                            EMIN(EMAX(d2, Kc2), EMAX(d3, Kc3)))))

#define BMOF(MX)                                                                \
  ({                                                                            \
    const unsigned long long mb_ = __builtin_bit_cast(unsigned long long, MX);  \
    const unsigned int ml_ = (unsigned int)mb_, mh_ = (unsigned int)(mb_ >> 32);\
    max(max((int)(ml_ & 0xFFFFu), (int)(ml_ >> 16)),                            \
        max((int)(mh_ & 0xFFFFu), (int)(mh_ >> 16)));                           \
  })

// ---------- Kernel B: column transform + SWAR epilogue, 32-col x 128-row tiles ----
__global__ __launch_bounds__(256) void k_fused(const unsigned char* __restrict__ d1,
                                               float* __restrict__ out) {
  const int ch = blockIdx.z;
  const int yt = blockIdx.y;  // 0..1
  const int xt = blockIdx.x;  // 0..7
  const int x0 = xt * 32;
  const int y0 = yt * 128;
  const int tid = threadIdx.x;
  const int lastxt = (int)gridDim.x - 1;

  // s1: u16, 279 rows (11 pad + 256 + 12 pad) x 48 cols (96 B); s1row = imgrow+11
  __shared__ __align__(16) unsigned char s1[279 * 96];
  __shared__ __align__(16) unsigned char Ds[136 * 44];  // u8; row r <-> y=y0+r-3

  // ---- fill pad rows (127) ----
  for (int i = tid; i < 552; i += 256) {
    const int r = (i * 2731) >> 16;  // /24
    const int c = i - r * 24;
    const int row = (r < 11) ? r : r + 256;  // 0..10, 267..278
    *reinterpret_cast<unsigned int*>(&s1[row * 96 + c * 4]) = 0x007F007Fu;
  }
  // ---- stage u8 d1 (48 cols, 256 rows), expand to u16 via perm ----
  const unsigned char* src = d1 + (size_t)ch * CHB + x0;
#pragma unroll
  for (int it = 0; it < 3; ++it) {
    const int idx = it * 256 + tid;     // 0..767
    const int y = (idx * 21846) >> 16;  // /3
    const int seg = idx - y * 3;
    const uint4 q = *reinterpret_cast<const uint4*>(&src[y * ROWB + seg * 16]);
    uint4 lo, hi;
    lo.x = __builtin_amdgcn_perm(0u, q.x, 0x0C010C00u);
    lo.y = __builtin_amdgcn_perm(0u, q.x, 0x0C030C02u);
    lo.z = __builtin_amdgcn_perm(0u, q.y, 0x0C010C00u);
    lo.w = __builtin_amdgcn_perm(0u, q.y, 0x0C030C02u);
    hi.x = __builtin_amdgcn_perm(0u, q.z, 0x0C010C00u);
    hi.y = __builtin_amdgcn_perm(0u, q.z, 0x0C030C02u);
    hi.z = __builtin_amdgcn_perm(0u, q.w, 0x0C010C00u);
    hi.w = __builtin_amdgcn_perm(0u, q.w, 0x0C030C02u);
    *reinterpret_cast<uint4*>(&s1[(y + 11) * 96 + seg * 32]) = lo;
    *reinterpret_cast<uint4*>(&s1[(y + 11) * 96 + seg * 32 + 16]) = hi;
  }
  __syncthreads();

  // ---- column pass: 27 rowgroups (5 rows each) x 10 quads = 270 tasks ----
  const u16x4 K1 = {1, 1, 1, 1}, K2 = {2, 2, 2, 2}, K3 = {3, 3, 3, 3},
              K4 = {4, 4, 4, 4}, K5 = {5, 5, 5, 5}, K6 = {6, 6, 6, 6},
              K7 = {7, 7, 7, 7}, K8 = {8, 8, 8, 8};
#pragma unroll 1
  for (int t = tid; t < 270; t += 256) {
    const int rg5 = (t * 6554) >> 16;  // /10
    const int g = t - rg5 * 10;        // quad 0..9 (cols x0-4+4g ..)
    const int r0r = rg5 * 5;           // Ds row base (0..130)
    const int ybase = y0 + r0r - 3;    // img y of output j=0
    const int dsb = r0r * 44 + g * 4;
    if ((xt == 0 && g == 0) || (xt == lastxt && g == 9)) {  // ghost columns
      *reinterpret_cast<unsigned int*>(&Ds[dsb]) = 0x7F7F7F7Fu;
      *reinterpret_cast<unsigned int*>(&Ds[dsb + 44]) = 0x7F7F7F7Fu;
      *reinterpret_cast<unsigned int*>(&Ds[dsb + 88]) = 0x7F7F7F7Fu;
      *reinterpret_cast<unsigned int*>(&Ds[dsb + 132]) = 0x7F7F7F7Fu;
      *reinterpret_cast<unsigned int*>(&Ds[dsb + 176]) = 0x7F7F7F7Fu;
      continue;
    }
    const int jb = 8 + 8 * g;
    const int ab = (ybase + 3) * 96 + jb;  // s1 addr of img row ybase-8 (>=0)
    // shared 21-row register window (offset-immediate ds_reads)
    const u16x4 w0 = LDQ(ab), w1 = LDQ(ab + 96), w2 = LDQ(ab + 192),
                w3 = LDQ(ab + 288), w4 = LDQ(ab + 384), w5 = LDQ(ab + 480),
                w6 = LDQ(ab + 576), w7 = LDQ(ab + 672), w8 = LDQ(ab + 768),
                w9 = LDQ(ab + 864), w10 = LDQ(ab + 960), w11 = LDQ(ab + 1056),
                w12 = LDQ(ab + 1152), w13 = LDQ(ab + 1248), w14 = LDQ(ab + 1344),
                w15 = LDQ(ab + 1440), w16 = LDQ(ab + 1536), w17 = LDQ(ab + 1632),
                w18 = LDQ(ab + 1728), w19 = LDQ(ab + 1824), w20 = LDQ(ab + 1920);
    PFX(o0, w0, w1, w2, w3, w4, w5, w6, w7, w8, w9, w10, w11, w12, w13, w14, w15, w16);
    PFX(o1, w1, w2, w3, w4, w5, w6, w7, w8, w9, w10, w11, w12, w13, w14, w15, w16, w17);
    PFX(o2, w2, w3, w4, w5, w6, w7, w8, w9, w10, w11, w12, w13, w14, w15, w16, w17, w18);
    PFX(o3, w3, w4, w5, w6, w7, w8, w9, w10, w11, w12, w13, w14, w15, w16, w17, w18, w19);
    PFX(o4, w4, w5, w6, w7, w8, w9, w10, w11, w12, w13, w14, w15, w16, w17, w18, w19, w20);
    u16x4 mx = EMAX(EMAX(o0, o1), EMAX(EMAX(o2, o3), o4));
    int bm = BMOF(mx);
    int kc = 9;
    while (kc < bm) {  // over-iterations are provable no-ops; pads are neutral 127
      const unsigned short q0 = (unsigned short)kc, q1 = (unsigned short)(kc + 1),
                           q2 = (unsigned short)(kc + 2), q3 = (unsigned short)(kc + 3);
      const u16x4 Kc0 = {q0, q0, q0, q0}, Kc1 = {q1, q1, q1, q1},
                  Kc2 = {q2, q2, q2, q2}, Kc3 = {q3, q3, q3, q3};
      const int lo = jb, hi = 278 * 96 + jb;
      const int aup = (ybase - kc + 8) * 96 + jb;  // s1 addr of up row m=0 (img ybase-kc-3)
      const int adn = (ybase + kc + 11) * 96 + jb; // s1 addr of down row m=0 (img ybase+kc)
      const u16x4 t0 = LDQ(max(aup, lo)), t1 = LDQ(max(aup + 96, lo)),
                  t2 = LDQ(max(aup + 192, lo)), t3 = LDQ(max(aup + 288, lo)),
                  t4 = LDQ(max(aup + 384, lo)), t5 = LDQ(max(aup + 480, lo)),
                  t6 = LDQ(max(aup + 576, lo)), t7 = LDQ(max(aup + 672, lo));
      const u16x4 u0 = LDQ(min(adn, hi)), u1 = LDQ(min(adn + 96, hi)),
                  u2 = LDQ(min(adn + 192, hi)), u3 = LDQ(min(adn + 288, hi)),
                  u4 = LDQ(min(adn + 384, hi)), u5 = LDQ(min(adn + 480, hi)),
                  u6 = LDQ(min(adn + 576, hi)), u7 = LDQ(min(adn + 672, hi));
      TUP(o0, t3, t2, t1, t0, u0, u1, u2, u3);
      TUP(o1, t4, t3, t2, t1, u1, u2, u3, u4);
      TUP(o2, t5, t4, t3, t2, u2, u3, u4, u5);
      TUP(o3, t6, t5, t4, t3, u3, u4, u5, u6);
      TUP(o4, t7, t6, t5, t4, u4, u5, u6, u7);
      kc += 4;
      mx = EMAX(EMAX(o0, o1), EMAX(EMAX(o2, o3), o4));
      bm = BMOF(mx);
    }
#define STROW(j_, OJ)                                                           \
    {                                                                           \
      const unsigned long long ob = __builtin_bit_cast(unsigned long long, OJ); \
      unsigned int packed = __builtin_amdgcn_perm(                              \
          (unsigned int)(ob >> 32), (unsigned int)ob, 0x06040200u);             \
      if ((unsigned int)(ybase + (j_)) > 255u) packed = 0x7F7F7F7Fu;            \
      *reinterpret_cast<unsigned int*>(&Ds[dsb + (j_) * 44]) = packed;          \
    }
    STROW(0, o0); STROW(1, o1); STROW(2, o2); STROW(3, o3); STROW(4, o4);
#undef STROW
  }
  __syncthreads();

  // ---- SWAR epilogue: thread tile = 4 cols x 4 rows; fully macro-unrolled ----
  const float wA = 3.17814e-2f, wB = 2.35426e-3f, wC = 1.91126e-4f, wD = 1.35150e-5f;
  const float W4 = 8.0f * wA + 12.0f * wB + 16.0f * wC + 12.0f * wD;

  const int cg = tid & 7;   // col group: center cols x0+4cg .. +3
  const int rg = tid >> 3;  // 0..31 (4 rows each)
  const int rl0 = rg * 4;   // local Ds row base
  const int jb2 = cg * 4;
  const size_t obase = (size_t)ch * 65536 + (size_t)(y0 + rl0) * 256 + x0 + cg * 4;

  unsigned int R[10][3];
#pragma unroll
  for (int u = 0; u < 10; ++u) {
    const unsigned char* p = &Ds[(rl0 + u) * 44 + jb2];
    R[u][0] = *reinterpret_cast<const unsigned int*>(p);
    R[u][1] = *reinterpret_cast<const unsigned int*>(p + 4);
    R[u][2] = *reinterpret_cast<const unsigned int*>(p + 8);
  }

  EPI(0); EPI(1); EPI(2); EPI(3);
}

extern "C" void kernel_launch(void* const* d_in, const int* in_sizes, int n_in,
                              void* d_out, int out_size, void* d_ws, size_t ws_size,
                              hipStream_t stream) {
  const float* img = (const float*)d_in[0];
  float* out = (float*)d_out;
  unsigned char* Dbuf = (unsigned char*)d_ws;

  const int total = in_sizes[0];  // B*C*H*W
  const int nch = total >> 16;    // B*C (H=W=256)

  k_rowdist<<<dim3(nch * 64), dim3(256), 0, stream>>>(img, Dbuf);
  k_fused<<<dim3(8, 2, nch), dim3(256), 0, stream>>>(Dbuf, out);
}